// Round 10
// baseline (330.410 us; speedup 1.0000x reference)
//
#include <hip/hip_runtime.h>
#include <hip/hip_bf16.h>

#define BATCH 8
#define LSEQ 2048
#define DDIM 512

using f32x4 = __attribute__((ext_vector_type(4))) float;
using s16x8 = __attribute__((ext_vector_type(8))) short;
using s16x4 = __attribute__((ext_vector_type(4))) short;

static __device__ __forceinline__ unsigned short f2b(float f) {
  __hip_bfloat16 h = __float2bfloat16(f);
  return __builtin_bit_cast(unsigned short, h);
}
static __device__ __forceinline__ float b2f(unsigned short u) {
  unsigned int v = ((unsigned int)u) << 16;
  return __builtin_bit_cast(float, v);
}

// async global->LDS, 16B per lane. LDS dest = wave-uniform base + lane*16.
static __device__ __forceinline__ void gld16(const unsigned short* g, unsigned short* l) {
  __builtin_amdgcn_global_load_lds(
      (__attribute__((address_space(1))) void*)(g),
      (__attribute__((address_space(3))) void*)(l), 16, 0, 0);
}

// 128x128-tile bf16 MFMA K-loop, async staging, single-buffered (R1-verified:
// dbuf measured neutral here and costs LDS/occupancy). 256 threads = 4 waves.
__device__ __forceinline__ void mfma_kloop(
    const unsigned short* __restrict__ A, const unsigned short* __restrict__ Bt,
    int K, int lda, int ldb, unsigned short* sA, unsigned short* sB,
    int tid, f32x4 acc[4][4]) {
  const int wave = tid >> 6, lane = tid & 63;
  const int wm = (wave >> 1) * 64, wn = (wave & 1) * 64;
  const int lr = lane & 15, lq = lane >> 4;
  const int srow = tid >> 2;       // 0..63
  const int sk = (tid & 3) * 8;    // 0,8,16,24
  unsigned short* dA0 = sA + wave * 512;          // + implicit lane*8
  unsigned short* dA1 = sA + 2048 + wave * 512;
  unsigned short* dB0 = sB + wave * 512;
  unsigned short* dB1 = sB + 2048 + wave * 512;
  const unsigned short* pa0 = A + (size_t)srow * lda + sk;
  const unsigned short* pa1 = A + (size_t)(srow + 64) * lda + sk;
  const unsigned short* pb0 = Bt + (size_t)srow * ldb + sk;
  const unsigned short* pb1 = Bt + (size_t)(srow + 64) * ldb + sk;
  for (int k0 = 0; k0 < K; k0 += 32) {
    gld16(pa0 + k0, dA0);
    gld16(pa1 + k0, dA1);
    gld16(pb0 + k0, dB0);
    gld16(pb1 + k0, dB1);
    __syncthreads();
    s16x8 af[4], bf[4];
#pragma unroll
    for (int r = 0; r < 4; ++r)
      af[r] = *(const s16x8*)(sA + (wm + r * 16 + lr) * 32 + lq * 8);
#pragma unroll
    for (int c = 0; c < 4; ++c)
      bf[c] = *(const s16x8*)(sB + (wn + c * 16 + lr) * 32 + lq * 8);
#pragma unroll
    for (int r = 0; r < 4; ++r)
#pragma unroll
      for (int c = 0; c < 4; ++c)
        acc[r][c] = __builtin_amdgcn_mfma_f32_16x16x32_bf16(af[r], bf[c], acc[r][c], 0, 0, 0);
    __syncthreads();
  }
}

// Fused f32->bf16 convert + masked partial sum. z selects input a/b.
__global__ __launch_bounds__(256) void k_prep(const float* __restrict__ in_a,
                                              const float* __restrict__ in_b,
                                              const int* __restrict__ ma,
                                              const int* __restrict__ mb,
                                              unsigned short* __restrict__ oa,
                                              unsigned short* __restrict__ ob,
                                              float* __restrict__ Pa,
                                              float* __restrict__ Pb) {
  int z = blockIdx.z;
  const float* in = z ? in_b : in_a;
  const int* mask = z ? mb : ma;
  unsigned short* o16 = z ? ob : oa;
  float* partial = z ? Pb : Pa;
  int b = blockIdx.y;
  int l0 = blockIdx.x * 32;
  __shared__ int sm[32];
  if (threadIdx.x < 32) sm[threadIdx.x] = mask[b * LSEQ + l0 + threadIdx.x];
  __syncthreads();
  int d = threadIdx.x * 2;
  const float* base = in + ((size_t)b * LSEQ + l0) * DDIM + d;
  unsigned short* obase = o16 + ((size_t)b * LSEQ + l0) * DDIM + d;
  float ax = 0.f, ay = 0.f;
#pragma unroll 4
  for (int r = 0; r < 32; ++r) {
    float2 v = *(const float2*)(base + (size_t)r * DDIM);
    ushort2 u; u.x = f2b(v.x); u.y = f2b(v.y);
    *(ushort2*)(obase + (size_t)r * DDIM) = u;
    if (sm[r] == 0) { ax += v.x; ay += v.y; }
  }
  float2 o; o.x = ax; o.y = ay;
  *(float2*)(partial + ((size_t)(b * 64 + blockIdx.x)) * DDIM + d) = o;
}

// Stage 2 for both inputs: C[b,d] = (1/L)*sum partials. grid 16.
__global__ __launch_bounds__(256) void k_p2(const float* __restrict__ Pa,
                                            const float* __restrict__ Pb,
                                            float* __restrict__ Ca,
                                            float* __restrict__ Cb) {
  int g = blockIdx.x;
  const float* src = (g < 8) ? Pa : Pb;
  float* dst = (g < 8) ? Ca : Cb;
  int b = g & 7;
  int d = threadIdx.x * 2;
  float ax = 0.f, ay = 0.f;
  for (int c = 0; c < 64; ++c) {
    float2 v = *(const float2*)(src + ((size_t)(b * 64 + c)) * DDIM + d);
    ax += v.x; ay += v.y;
  }
  dst[b * DDIM + d] = ax * (1.0f / LSEQ);
  dst[b * DDIM + d + 1] = ay * (1.0f / LSEQ);
}

// Both weights [D,H] f32 -> [H,D] bf16. grid 2048 covers 2x512x512.
__global__ __launch_bounds__(256) void k_transposeW(const float* __restrict__ Wa,
                                                    const float* __restrict__ Wb,
                                                    unsigned short* __restrict__ WaT,
                                                    unsigned short* __restrict__ WbT) {
  int gidx = blockIdx.x * 256 + threadIdx.x;
  const float* W = (gidx < 512 * 512) ? Wa : Wb;
  unsigned short* WT = (gidx < 512 * 512) ? WaT : WbT;
  int idx = gidx & (512 * 512 - 1);
  int h = idx >> 9, d = idx & 511;
  WT[idx] = f2b(W[d * DDIM + h]);
}

// mapped = A(bf16) @ W^T(bf16) + bias -> bf16. 1-D grid 1024, XCD-swizzled.
__global__ __launch_bounds__(256) void k_gemm_bias(const unsigned short* __restrict__ a16,
                                                   const unsigned short* __restrict__ b16,
                                                   const unsigned short* __restrict__ WaT,
                                                   const unsigned short* __restrict__ WbT,
                                                   const float* __restrict__ ba,
                                                   const float* __restrict__ bb,
                                                   unsigned short* __restrict__ mapa,
                                                   unsigned short* __restrict__ mapb) {
  int id = blockIdx.x;
  int g = id >> 5, rem = id & 31;
  int bn = (rem >> 3) * 128;
  int f = g * 8 + (rem & 7);   // 0..255
  int bm = (f & 127) * 128;
  int z = f >> 7;
  const unsigned short* A = z ? b16 : a16;
  const unsigned short* Bt = z ? WbT : WaT;
  const float* bias = z ? bb : ba;
  unsigned short* Cout = z ? mapb : mapa;
  __shared__ __align__(16) unsigned short sA[128 * 32], sB[128 * 32];
  f32x4 acc[4][4];
  f32x4 zero = {0.f, 0.f, 0.f, 0.f};
#pragma unroll
  for (int r = 0; r < 4; ++r)
#pragma unroll
    for (int c = 0; c < 4; ++c) acc[r][c] = zero;
  mfma_kloop(A + (size_t)bm * DDIM, Bt + (size_t)bn * DDIM, DDIM, DDIM, DDIM,
             sA, sB, threadIdx.x, acc);
  int wave = threadIdx.x >> 6, lane = threadIdx.x & 63;
  int wm = (wave >> 1) * 64, wn = (wave & 1) * 64, lr = lane & 15, lq = lane >> 4;
#pragma unroll
  for (int r = 0; r < 4; ++r)
#pragma unroll
    for (int c = 0; c < 4; ++c)
#pragma unroll
      for (int rr = 0; rr < 4; ++rr) {
        int row = bm + wm + r * 16 + lq * 4 + rr;
        int col = bn + wn + c * 16 + lr;
        Cout[(size_t)row * DDIM + col] = f2b(acc[r][c][rr] + bias[col]);
      }
}

// Scores on the verified 8-phase 256x256 template (same ring as k_gemm_outs,
// NT=16): E = mask ? exp(scale*mapa.mapb^T) : 0 (bf16) + fused row/col sums
// (shfl + atomics) + Et = E^T via full-tile bounce reusing the dead ring LDS.
// Grid 512: 64 consecutive work-ids per XCD = one full batch b (L2 locality).
__global__ __launch_bounds__(512, 2) void k_scores(
    const unsigned short* __restrict__ mapa, const unsigned short* __restrict__ mapb,
    const int* __restrict__ mask_a, const int* __restrict__ mask_b,
    unsigned short* __restrict__ E, unsigned short* __restrict__ Et,
    float* __restrict__ Zrow, float* __restrict__ Zcol) {
  int w = (blockIdx.x & 7) * 64 + (blockIdx.x >> 3);
  int b = w >> 6, t = w & 63;
  int bi = (t >> 3) * 256, bj = (t & 7) * 256;
  const unsigned short* Aop = mapa + ((size_t)b * LSEQ + bi) * DDIM;
  const unsigned short* Bop = mapb + ((size_t)b * LSEQ + bj) * DDIM;

  __shared__ __align__(16) unsigned short smem[65536];  // 128KB: ring, then bounce
  unsigned short* sA = smem;
  unsigned short* sB = smem + 32768;
  __shared__ int sMa[256], sMb[256];

  const int tid = threadIdx.x;
  const int wave = tid >> 6, lane = tid & 63;
  const int wr = wave >> 2, wc = wave & 3;
  const int lr = lane & 15, lq = lane >> 4;

  const int srow = tid >> 2;                       // 0..127
  const int kcsw = ((tid & 3) ^ (srow & 3)) * 8;   // swizzled k sub-chunk
  const unsigned short* pa0 = Aop + (size_t)srow * DDIM + kcsw;
  const unsigned short* pa1 = pa0 + (size_t)128 * DDIM;
  const unsigned short* pb0 = Bop + (size_t)srow * DDIM + kcsw;
  const unsigned short* pb1 = pb0 + (size_t)128 * DDIM;
  unsigned short* dA = sA + wave * 512;            // + implicit lane*8 shorts
  unsigned short* dB = sB + wave * 512;

  int aoff[8], boff[4];
#pragma unroll
  for (int m = 0; m < 8; ++m)
    aoff[m] = (wr * 128 + m * 16 + lr) * 32 + (lq ^ (lr & 3)) * 8;
#pragma unroll
  for (int n = 0; n < 4; ++n)
    boff[n] = (wc * 64 + n * 16 + lr) * 32 + (lq ^ (lr & 3)) * 8;

  f32x4 acc[8][4];
  f32x4 zero = {0.f, 0.f, 0.f, 0.f};
#pragma unroll
  for (int m = 0; m < 8; ++m)
#pragma unroll
    for (int n = 0; n < 4; ++n) acc[m][n] = zero;

#define SGA(c) { const int sl_ = ((c) & 3) * 8192; \
  gld16(pa0 + (size_t)(c) * 32, dA + sl_); \
  gld16(pa1 + (size_t)(c) * 32, dA + sl_ + 4096); }
#define SGB(c) { const int sl_ = ((c) & 3) * 8192; \
  gld16(pb0 + (size_t)(c) * 32, dB + sl_); \
  gld16(pb1 + (size_t)(c) * 32, dB + sl_ + 4096); }

  // prologue: chunks 0..2 in flight, wait for chunk 0 (oldest 4 ops of 12).
  SGA(0); SGB(0); SGA(1); SGB(1); SGA(2); SGB(2);
  asm volatile("s_waitcnt vmcnt(8)\ns_barrier" ::: "memory");

  for (int j = 0; j < 16; ++j) {
    const int sl = (j & 3) * 8192;
    s16x8 af[8];
#pragma unroll
    for (int m = 0; m < 8; ++m) af[m] = *(const s16x8*)(sA + sl + aoff[m]);
    s16x8 bf0 = *(const s16x8*)(sB + sl + boff[0]);
    s16x8 bf1 = *(const s16x8*)(sB + sl + boff[1]);
    if (j < 13) SGA(j + 3);
    __builtin_amdgcn_s_setprio(1);
#pragma unroll
    for (int m = 0; m < 8; ++m) {
      acc[m][0] = __builtin_amdgcn_mfma_f32_16x16x32_bf16(af[m], bf0, acc[m][0], 0, 0, 0);
      acc[m][1] = __builtin_amdgcn_mfma_f32_16x16x32_bf16(af[m], bf1, acc[m][1], 0, 0, 0);
    }
    __builtin_amdgcn_s_setprio(0);
    asm volatile("s_barrier" ::: "memory");
    s16x8 bf2 = *(const s16x8*)(sB + sl + boff[2]);
    s16x8 bf3 = *(const s16x8*)(sB + sl + boff[3]);
    if (j < 13) SGB(j + 3);
    __builtin_amdgcn_s_setprio(1);
#pragma unroll
    for (int m = 0; m < 8; ++m) {
      acc[m][2] = __builtin_amdgcn_mfma_f32_16x16x32_bf16(af[m], bf2, acc[m][2], 0, 0, 0);
      acc[m][3] = __builtin_amdgcn_mfma_f32_16x16x32_bf16(af[m], bf3, acc[m][3], 0, 0, 0);
    }
    __builtin_amdgcn_s_setprio(0);
    if (j < 13)
      asm volatile("s_waitcnt vmcnt(8)\ns_barrier" ::: "memory");
    else if (j == 13)
      asm volatile("s_waitcnt vmcnt(4)\ns_barrier" ::: "memory");
    else
      asm volatile("s_waitcnt vmcnt(0)\ns_barrier" ::: "memory");
  }
#undef SGA
#undef SGB

  // masks -> LDS after the ring drains (zero vmcnt interference).
  if (tid < 256)
    sMa[tid] = mask_a[b * LSEQ + bi + tid];
  else
    sMb[tid - 256] = mask_b[b * LSEQ + bj + tid - 256];
  __syncthreads();

  const float scale = 0.044194173824159216f;  // 1/sqrt(512)
  unsigned short* Eb = E + (size_t)b * LSEQ * LSEQ + (size_t)bi * LSEQ + bj;
  float rowp[8][4];
  float colp[4] = {0.f, 0.f, 0.f, 0.f};
#pragma unroll
  for (int m = 0; m < 8; ++m) {
#pragma unroll
    for (int rr = 0; rr < 4; ++rr) rowp[m][rr] = 0.f;
#pragma unroll
    for (int n = 0; n < 4; ++n) {
      int jl = wc * 64 + n * 16 + lr;
      int mb_ = sMb[jl];
      s16x4 tq;
#pragma unroll
      for (int rr = 0; rr < 4; ++rr) {
        int il = wr * 128 + m * 16 + lq * 4 + rr;
        float e = (sMa[il] && mb_) ? __expf(acc[m][n][rr] * scale) : 0.f;
        rowp[m][rr] += e;
        colp[n] += e;
        unsigned short eb = f2b(e);
        tq[rr] = (short)eb;
        Eb[(size_t)il * LSEQ + jl] = eb;   // scalar, L2 write-combined
      }
      // write-through to bounce [jl][il^swz]; x=(jl&7)*8 preserves 8-runs
      int il0 = wr * 128 + m * 16 + lq * 4;
      *(s16x4*)(smem + jl * 256 + (il0 ^ ((jl & 7) << 3))) = tq;
    }
  }
#pragma unroll
  for (int m = 0; m < 8; ++m)
#pragma unroll
    for (int rr = 0; rr < 4; ++rr) {
      float v = rowp[m][rr];
      v += __shfl_xor(v, 1);
      v += __shfl_xor(v, 2);
      v += __shfl_xor(v, 4);
      v += __shfl_xor(v, 8);
      if (lr == 0) {
        int il = wr * 128 + m * 16 + lq * 4 + rr;
        atomicAdd(&Zrow[b * LSEQ + bi + il], v);
      }
    }
#pragma unroll
  for (int n = 0; n < 4; ++n) {
    float v = colp[n];
    v += __shfl_xor(v, 16);
    v += __shfl_xor(v, 32);
    if (lq == 0) atomicAdd(&Zcol[b * LSEQ + bj + wc * 64 + n * 16 + lr], v);
  }
  __syncthreads();
  // Et pass: 256 rows x 32 chunks of 16B, coalesced; inverse XOR recovers il.
  unsigned short* EtB = Et + (size_t)b * LSEQ * LSEQ + (size_t)bj * LSEQ + bi;
#pragma unroll
  for (int p = 0; p < 16; ++p) {
    int idx = p * 512 + tid;
    int jlr = idx >> 5, chk = idx & 31;
    s16x8 v = *(const s16x8*)(smem + jlr * 256 + ((chk * 8) ^ ((jlr & 7) << 3)));
    *(s16x8*)(EtB + (size_t)jlr * LSEQ + chk * 8) = v;
  }
}

// out[b,d,i] = (Z[b,i]>0 ? 1/Z[b,i] : 0) * in16[b,i,d], transposed store.
__global__ __launch_bounds__(256) void k_scaleT(const unsigned short* __restrict__ a16,
                                                const unsigned short* __restrict__ b16,
                                                const float* __restrict__ Zrow,
                                                const float* __restrict__ Zcol,
                                                unsigned short* __restrict__ atS,
                                                unsigned short* __restrict__ btS) {
  int zz = blockIdx.z;
  int b = zz & 7, sel = zz >> 3;
  const unsigned short* in = sel ? b16 : a16;
  const float* Z = sel ? Zcol : Zrow;
  unsigned short* out = sel ? btS : atS;
  int i0 = blockIdx.y * 64, d0 = blockIdx.x * 64;
  __shared__ unsigned short lt[64 * 65];
  __shared__ float zinv[64];
  if (threadIdx.x < 64) {
    float z = Z[b * LSEQ + i0 + threadIdx.x];
    zinv[threadIdx.x] = (z > 0.f) ? 1.f / z : 0.f;
  }
  __syncthreads();
  const unsigned short* ib = in + ((size_t)b * LSEQ + i0) * DDIM + d0;
#pragma unroll
  for (int p = 0; p < 16; ++p) {
    int idx = p * 256 + threadIdx.x;
    int dl = idx & 63, il = idx >> 6;
    lt[dl * 65 + il] = f2b(b2f(ib[(size_t)il * DDIM + dl]) * zinv[il]);
  }
  __syncthreads();
  unsigned short* ob = out + ((size_t)b * DDIM + d0) * LSEQ + i0;
#pragma unroll
  for (int p = 0; p < 16; ++p) {
    int idx = p * 256 + threadIdx.x;
    int il = idx & 63, dl = idx >> 6;
    ob[(size_t)dl * LSEQ + il] = lt[dl * 65 + il];
  }
}

// Output GEMMs, 256x256 tile, 8 waves, 8-phase K-chunk ring (T2+T3+T4+T5):
//   mode0: OutA = E  @ btS^T + a16 + Cb
//   mode1: OutB = Et @ atS^T + b16 + Ca
// K-chunk = 32; ring of 4 chunk slots per operand (4x16KB A + 4x16KB B = 128KB).
// Stages lead reads by 3 chunks; counted s_waitcnt vmcnt(8) (never 0 until tail).
// XOR swizzle kc ^= (row&3) on staged source + ds_read deconflicts banks.
// Grid 256 (1 block/CU), 512 threads (2M x 4N waves), 128x64 out per wave.
__global__ __launch_bounds__(512, 2) void k_gemm_outs(
    const unsigned short* __restrict__ E, const unsigned short* __restrict__ Et,
    const unsigned short* __restrict__ btS, const unsigned short* __restrict__ atS,
    const unsigned short* __restrict__ a16, const unsigned short* __restrict__ b16,
    const float* __restrict__ Ca, const float* __restrict__ Cb,
    float* __restrict__ OutA, float* __restrict__ OutB) {
  // XCD swizzle: 32 consecutive work ids per XCD -> 2 full (mode,b) instances/XCD.
  int w = (blockIdx.x & 7) * 32 + (blockIdx.x >> 3);
  int mode = w >> 7;
  int r0 = w & 127;
  int b = r0 >> 4, tile = r0 & 15;
  int bm = (tile >> 1) * 256, bn = (tile & 1) * 256;
  const unsigned short* Aop = (mode ? Et : E) + (size_t)b * LSEQ * LSEQ + (size_t)bm * LSEQ;
  const unsigned short* Bop = (mode ? atS : btS) + (size_t)b * DDIM * LSEQ + (size_t)bn * LSEQ;
  const unsigned short* addin = mode ? b16 : a16;
  const float* Cvec = mode ? Ca : Cb;
  float* Out = mode ? OutB : OutA;

  __shared__ __align__(16) unsigned short sA[4 * 8192], sB[4 * 8192];
  const int tid = threadIdx.x;
  const int wave = tid >> 6, lane = tid & 63;
  const int wr = wave >> 2, wc = wave & 3;
  const int lr = lane & 15, lq = lane >> 4;

  // staging: chunk = [256 rows][32 k] bf16 = 16KB; thread covers 16B at linear
  // LDS offset tid*16 (+8192B for second row-half); source k-chunk XOR-swizzled.
  const int srow = tid >> 2;                       // 0..127
  const int kcsw = ((tid & 3) ^ (srow & 3)) * 8;   // swizzled k sub-chunk
  const unsigned short* pa0 = Aop + (size_t)srow * LSEQ + kcsw;
  const unsigned short* pa1 = pa0 + (size_t)128 * LSEQ;
  const unsigned short* pb0 = Bop + (size_t)srow * LSEQ + kcsw;
  const unsigned short* pb1 = pb0 + (size_t)128 * LSEQ;
  unsigned short* dA = sA + wave * 512;            // + implicit lane*8 shorts
  unsigned short* dB = sB + wave * 512;

  // fragment read offsets (shorts), same XOR swizzle
  int aoff[8], boff[4];
#pragma unroll
  for (int m = 0; m < 8; ++m)
    aoff[m] = (wr * 128 + m * 16 + lr) * 32 + (lq ^ (lr & 3)) * 8;
#pragma unroll
  for (int n = 0; n < 4; ++n)
    boff[n] = (wc * 64 + n * 16 + lr) * 32 + (lq ^ (lr & 3)) * 8;

  f32x4 acc[8][4];
  f32x4 zero = {0.f, 0.f, 0.f, 0.f};
#pragma unroll
  for (int m = 0; m < 8; ++m)
#pragma unroll
    for (int n = 0; n < 4; ++n) acc[m][n] = zero;

#define SGA(c) { const int sl_ = ((c) & 3) * 8192; \
  gld16(pa0 + (size_t)(c) * 32, dA + sl_); \
  gld16(pa1 + (size_t)(c) * 32, dA + sl_ + 4096); }
#define SGB(c) { const int sl_ = ((c) & 3) * 8192; \
  gld16(pb0 + (size_t)(c) * 32, dB + sl_); \
  gld16(pb1 + (size_t)(c) * 32, dB + sl_ + 4096); }

  // prologue: chunks 0..2 in flight, wait for chunk 0 (oldest 4 ops of 12).
  SGA(0); SGB(0); SGA(1); SGB(1); SGA(2); SGB(2);
  asm volatile("s_waitcnt vmcnt(8)\ns_barrier" ::: "memory");

  for (int j = 0; j < 64; ++j) {
    const int sl = (j & 3) * 8192;
    // EVEN phase: af(8) + bf01 reads, stage A(j+3), MFMA n=0,1
    s16x8 af[8];
#pragma unroll
    for (int m = 0; m < 8; ++m) af[m] = *(const s16x8*)(sA + sl + aoff[m]);
    s16x8 bf0 = *(const s16x8*)(sB + sl + boff[0]);
    s16x8 bf1 = *(const s16x8*)(sB + sl + boff[1]);
    if (j < 61) SGA(j + 3);
    __builtin_amdgcn_s_setprio(1);
#pragma unroll
    for (int m = 0; m < 8; ++m) {
      acc[m][0] = __builtin_amdgcn_mfma_f32_16x16x32_bf16(af[m], bf0, acc[m][0], 0, 0, 0);
      acc[m][1] = __builtin_amdgcn_mfma_f32_16x16x32_bf16(af[m], bf1, acc[m][1], 0, 0, 0);
    }
    __builtin_amdgcn_s_setprio(0);
    asm volatile("s_barrier" ::: "memory");
    // ODD phase: bf23 reads, stage B(j+3), MFMA n=2,3, counted wait + barrier
    s16x8 bf2 = *(const s16x8*)(sB + sl + boff[2]);
    s16x8 bf3 = *(const s16x8*)(sB + sl + boff[3]);
    if (j < 61) SGB(j + 3);
    __builtin_amdgcn_s_setprio(1);
#pragma unroll
    for (int m = 0; m < 8; ++m) {
      acc[m][2] = __builtin_amdgcn_mfma_f32_16x16x32_bf16(af[m], bf2, acc[m][2], 0, 0, 0);
      acc[m][3] = __builtin_amdgcn_mfma_f32_16x16x32_bf16(af[m], bf3, acc[m][3], 0, 0, 0);
    }
    __builtin_amdgcn_s_setprio(0);
    if (j < 61)
      asm volatile("s_waitcnt vmcnt(8)\ns_barrier" ::: "memory");
    else if (j == 61)
      asm volatile("s_waitcnt vmcnt(4)\ns_barrier" ::: "memory");
    else
      asm volatile("s_waitcnt vmcnt(0)\ns_barrier" ::: "memory");
  }
#undef SGA
#undef SGB

#pragma unroll
  for (int m = 0; m < 8; ++m)
#pragma unroll
    for (int n = 0; n < 4; ++n)
#pragma unroll
      for (int rr = 0; rr < 4; ++rr) {
        int row = bm + wr * 128 + m * 16 + lq * 4 + rr;
        int col = bn + wc * 64 + n * 16 + lr;
        size_t o = ((size_t)b * LSEQ + row) * DDIM + col;
        Out[o] = acc[m][n][rr] + b2f(addin[o]) + Cvec[b * DDIM + col];
      }
}

extern "C" void kernel_launch(void* const* d_in, const int* in_sizes, int n_in,
                              void* d_out, int out_size, void* d_ws, size_t ws_size,
                              hipStream_t stream) {
  (void)in_sizes; (void)n_in; (void)out_size; (void)ws_size;
  const float* in_a = (const float*)d_in[0];
  const float* in_b = (const float*)d_in[1];
  const int* ma = (const int*)d_in[2];
  const int* mb = (const int*)d_in[3];
  const float* Wa = (const float*)d_in[4];
  const float* ba = (const float*)d_in[5];
  const float* Wb = (const float*)d_in[6];
  const float* bb = (const float*)d_in[7];
  float* out = (float*)d_out;

  char* ws = (char*)d_ws;
  const size_t MB = 1ull << 20;
  unsigned short* a16 = (unsigned short*)(ws + 0 * MB);    // 16MB
  unsigned short* b16 = (unsigned short*)(ws + 16 * MB);   // 16MB
  unsigned short* WaT = (unsigned short*)(ws + 32 * MB);   // 0.5MB
  unsigned short* WbT = (unsigned short*)(ws + 32 * MB + 512 * 1024);
  unsigned short* mapa = (unsigned short*)(ws + 33 * MB);  // 16MB
  unsigned short* mapb = (unsigned short*)(ws + 49 * MB);  // 16MB
  unsigned short* E = (unsigned short*)(ws + 65 * MB);     // 64MB
  unsigned short* atS = (unsigned short*)(ws + 129 * MB);  // 16MB
  unsigned short* btS = (unsigned short*)(ws + 145 * MB);  // 16MB
  float* Zrow = (float*)(ws + 161 * MB);                   // 64KB
  float* Zcol = (float*)(ws + 161 * MB + 65536);           // 64KB
  float* Ca = (float*)(ws + 161 * MB + 2 * 65536);         // 16KB
  float* Cb = (float*)(ws + 161 * MB + 2 * 65536 + 16384); // 16KB
  float* Pa = (float*)(ws + 162 * MB);                     // 1MB
  float* Pb = (float*)(ws + 163 * MB);                     // 1MB
  unsigned short* Et = (unsigned short*)(ws + 164 * MB);   // 64MB

  hipMemsetAsync(Zrow, 0, 2 * 65536, stream);  // Zrow + Zcol
  k_prep<<<dim3(64, 8, 2), 256, 0, stream>>>(in_a, in_b, ma, mb, a16, b16, Pa, Pb);
  k_transposeW<<<2048, 256, 0, stream>>>(Wa, Wb, WaT, WbT);
  k_p2<<<16, 256, 0, stream>>>(Pa, Pb, Ca, Cb);
  k_gemm_bias<<<1024, 256, 0, stream>>>(a16, b16, WaT, WbT, ba, bb, mapa, mapb);
  k_scores<<<512, 512, 0, stream>>>(mapa, mapb, ma, mb, E, Et, Zrow, Zcol);
  k_scaleT<<<dim3(8, 32, 16), 256, 0, stream>>>(a16, b16, Zrow, Zcol, atS, btS);
  k_gemm_outs<<<256, 512, 0, stream>>>(E, Et, btS, atS, a16, b16, Ca, Cb,
                                       out, out + (size_t)BATCH * LSEQ * DDIM);
}

// Round 15
// 318.561 us; speedup vs baseline: 1.0372x; 1.0372x over previous
//
#include <hip/hip_runtime.h>
#include <hip/hip_bf16.h>

#define BATCH 8
#define LSEQ 2048
#define DDIM 512

using f32x4 = __attribute__((ext_vector_type(4))) float;
using s16x8 = __attribute__((ext_vector_type(8))) short;
using s16x4 = __attribute__((ext_vector_type(4))) short;

static __device__ __forceinline__ unsigned short f2b(float f) {
  __hip_bfloat16 h = __float2bfloat16(f);
  return __builtin_bit_cast(unsigned short, h);
}
static __device__ __forceinline__ float b2f(unsigned short u) {
  unsigned int v = ((unsigned int)u) << 16;
  return __builtin_bit_cast(float, v);
}

// async global->LDS, 16B per lane. LDS dest = wave-uniform base + lane*16.
static __device__ __forceinline__ void gld16(const unsigned short* g, unsigned short* l) {
  __builtin_amdgcn_global_load_lds(
      (__attribute__((address_space(1))) void*)(g),
      (__attribute__((address_space(3))) void*)(l), 16, 0, 0);
}

// Fused f32->bf16 convert + masked mean via device-scope atomics (k_p2 folded in).
__global__ __launch_bounds__(256) void k_prep(const float* __restrict__ in_a,
                                              const float* __restrict__ in_b,
                                              const int* __restrict__ ma,
                                              const int* __restrict__ mb,
                                              unsigned short* __restrict__ oa,
                                              unsigned short* __restrict__ ob,
                                              float* __restrict__ Ca,
                                              float* __restrict__ Cb) {
  int z = blockIdx.z;
  const float* in = z ? in_b : in_a;
  const int* mask = z ? mb : ma;
  unsigned short* o16 = z ? ob : oa;
  float* cdst = z ? Cb : Ca;
  int b = blockIdx.y;
  int l0 = blockIdx.x * 32;
  __shared__ int sm[32];
  if (threadIdx.x < 32) sm[threadIdx.x] = mask[b * LSEQ + l0 + threadIdx.x];
  __syncthreads();
  int d = threadIdx.x * 2;
  const float* base = in + ((size_t)b * LSEQ + l0) * DDIM + d;
  unsigned short* obase = o16 + ((size_t)b * LSEQ + l0) * DDIM + d;
  float ax = 0.f, ay = 0.f;
#pragma unroll 4
  for (int r = 0; r < 32; ++r) {
    float2 v = *(const float2*)(base + (size_t)r * DDIM);
    ushort2 u; u.x = f2b(v.x); u.y = f2b(v.y);
    *(ushort2*)(obase + (size_t)r * DDIM) = u;
    if (sm[r] == 0) { ax += v.x; ay += v.y; }
  }
  if (ax != 0.f || ay != 0.f || true) {
    atomicAdd(&cdst[b * DDIM + d], ax * (1.0f / LSEQ));
    atomicAdd(&cdst[b * DDIM + d + 1], ay * (1.0f / LSEQ));
  }
}

// Both weights [D,H] f32 -> [H,D] bf16. grid 2048 covers 2x512x512.
__global__ __launch_bounds__(256) void k_transposeW(const float* __restrict__ Wa,
                                                    const float* __restrict__ Wb,
                                                    unsigned short* __restrict__ WaT,
                                                    unsigned short* __restrict__ WbT) {
  int gidx = blockIdx.x * 256 + threadIdx.x;
  const float* W = (gidx < 512 * 512) ? Wa : Wb;
  unsigned short* WT = (gidx < 512 * 512) ? WaT : WbT;
  int idx = gidx & (512 * 512 - 1);
  int h = idx >> 9, d = idx & 511;
  WT[idx] = f2b(W[d * DDIM + h]);
}

// mapped = A(bf16) @ W^T(bf16) + bias -> bf16, on the verified 8-phase 256x256
// template (NT=16 ring, same tail constants as k_scores). Grid 256, 1 block/CU.
__global__ __launch_bounds__(512, 2) void k_gemm_bias(
    const unsigned short* __restrict__ a16, const unsigned short* __restrict__ b16,
    const unsigned short* __restrict__ WaT, const unsigned short* __restrict__ WbT,
    const float* __restrict__ ba, const float* __restrict__ bb,
    unsigned short* __restrict__ mapa, unsigned short* __restrict__ mapb) {
  int w = (blockIdx.x & 7) * 32 + (blockIdx.x >> 3);  // 32 consecutive ids / XCD
  int z = w >> 7;
  int id = w & 127;
  int bmt = id >> 1;              // 0..63 M-tile
  int bn = (id & 1) * 256;
  int b = bmt >> 3;
  int row0 = (bmt & 7) * 256;
  const unsigned short* Aop = (z ? b16 : a16) + ((size_t)b * LSEQ + row0) * DDIM;
  const unsigned short* Bop = (z ? WbT : WaT) + (size_t)bn * DDIM;
  const float* bias = z ? bb : ba;
  unsigned short* Cout = (z ? mapb : mapa) + ((size_t)b * LSEQ + row0) * DDIM;

  __shared__ __align__(16) unsigned short sA[4 * 8192], sB[4 * 8192];
  const int tid = threadIdx.x;
  const int wave = tid >> 6, lane = tid & 63;
  const int wr = wave >> 2, wc = wave & 3;
  const int lr = lane & 15, lq = lane >> 4;

  const int srow = tid >> 2;                       // 0..127
  const int kcsw = ((tid & 3) ^ (srow & 3)) * 8;   // swizzled k sub-chunk
  const unsigned short* pa0 = Aop + (size_t)srow * DDIM + kcsw;
  const unsigned short* pa1 = pa0 + (size_t)128 * DDIM;
  const unsigned short* pb0 = Bop + (size_t)srow * DDIM + kcsw;
  const unsigned short* pb1 = pb0 + (size_t)128 * DDIM;
  unsigned short* dA = sA + wave * 512;
  unsigned short* dB = sB + wave * 512;

  int aoff[8], boff[4];
#pragma unroll
  for (int m = 0; m < 8; ++m)
    aoff[m] = (wr * 128 + m * 16 + lr) * 32 + (lq ^ (lr & 3)) * 8;
#pragma unroll
  for (int n = 0; n < 4; ++n)
    boff[n] = (wc * 64 + n * 16 + lr) * 32 + (lq ^ (lr & 3)) * 8;

  f32x4 acc[8][4];
  f32x4 zero = {0.f, 0.f, 0.f, 0.f};
#pragma unroll
  for (int m = 0; m < 8; ++m)
#pragma unroll
    for (int n = 0; n < 4; ++n) acc[m][n] = zero;

#define SGA(c) { const int sl_ = ((c) & 3) * 8192; \
  gld16(pa0 + (size_t)(c) * 32, dA + sl_); \
  gld16(pa1 + (size_t)(c) * 32, dA + sl_ + 4096); }
#define SGB(c) { const int sl_ = ((c) & 3) * 8192; \
  gld16(pb0 + (size_t)(c) * 32, dB + sl_); \
  gld16(pb1 + (size_t)(c) * 32, dB + sl_ + 4096); }

  SGA(0); SGB(0); SGA(1); SGB(1); SGA(2); SGB(2);
  asm volatile("s_waitcnt vmcnt(8)\ns_barrier" ::: "memory");

  for (int j = 0; j < 16; ++j) {
    const int sl = (j & 3) * 8192;
    s16x8 af[8];
#pragma unroll
    for (int m = 0; m < 8; ++m) af[m] = *(const s16x8*)(sA + sl + aoff[m]);
    s16x8 bf0 = *(const s16x8*)(sB + sl + boff[0]);
    s16x8 bf1 = *(const s16x8*)(sB + sl + boff[1]);
    if (j < 13) SGA(j + 3);
    __builtin_amdgcn_s_setprio(1);
#pragma unroll
    for (int m = 0; m < 8; ++m) {
      acc[m][0] = __builtin_amdgcn_mfma_f32_16x16x32_bf16(af[m], bf0, acc[m][0], 0, 0, 0);
      acc[m][1] = __builtin_amdgcn_mfma_f32_16x16x32_bf16(af[m], bf1, acc[m][1], 0, 0, 0);
    }
    __builtin_amdgcn_s_setprio(0);
    asm volatile("s_barrier" ::: "memory");
    s16x8 bf2 = *(const s16x8*)(sB + sl + boff[2]);
    s16x8 bf3 = *(const s16x8*)(sB + sl + boff[3]);
    if (j < 13) SGB(j + 3);
    __builtin_amdgcn_s_setprio(1);
#pragma unroll
    for (int m = 0; m < 8; ++m) {
      acc[m][2] = __builtin_amdgcn_mfma_f32_16x16x32_bf16(af[m], bf2, acc[m][2], 0, 0, 0);
      acc[m][3] = __builtin_amdgcn_mfma_f32_16x16x32_bf16(af[m], bf3, acc[m][3], 0, 0, 0);
    }
    __builtin_amdgcn_s_setprio(0);
    if (j < 13)
      asm volatile("s_waitcnt vmcnt(8)\ns_barrier" ::: "memory");
    else if (j == 13)
      asm volatile("s_waitcnt vmcnt(4)\ns_barrier" ::: "memory");
    else
      asm volatile("s_waitcnt vmcnt(0)\ns_barrier" ::: "memory");
  }
#undef SGA
#undef SGB

#pragma unroll
  for (int m = 0; m < 8; ++m)
#pragma unroll
    for (int n = 0; n < 4; ++n)
#pragma unroll
      for (int rr = 0; rr < 4; ++rr) {
        int row = wr * 128 + m * 16 + lq * 4 + rr;
        int col = bn + wc * 64 + n * 16 + lr;
        Cout[(size_t)row * DDIM + col] = f2b(acc[m][n][rr] + bias[col]);
      }
}

// Scores on the verified 8-phase 256x256 template (NT=16): E + fused row/col
// sums + Et via full-tile bounce reusing the dead ring LDS. Grid 512.
__global__ __launch_bounds__(512, 2) void k_scores(
    const unsigned short* __restrict__ mapa, const unsigned short* __restrict__ mapb,
    const int* __restrict__ mask_a, const int* __restrict__ mask_b,
    unsigned short* __restrict__ E, unsigned short* __restrict__ Et,
    float* __restrict__ Zrow, float* __restrict__ Zcol) {
  int w = (blockIdx.x & 7) * 64 + (blockIdx.x >> 3);
  int b = w >> 6, t = w & 63;
  int bi = (t >> 3) * 256, bj = (t & 7) * 256;
  const unsigned short* Aop = mapa + ((size_t)b * LSEQ + bi) * DDIM;
  const unsigned short* Bop = mapb + ((size_t)b * LSEQ + bj) * DDIM;

  __shared__ __align__(16) unsigned short smem[65536];  // 128KB: ring, then bounce
  unsigned short* sA = smem;
  unsigned short* sB = smem + 32768;
  __shared__ int sMa[256], sMb[256];

  const int tid = threadIdx.x;
  const int wave = tid >> 6, lane = tid & 63;
  const int wr = wave >> 2, wc = wave & 3;
  const int lr = lane & 15, lq = lane >> 4;

  const int srow = tid >> 2;                       // 0..127
  const int kcsw = ((tid & 3) ^ (srow & 3)) * 8;   // swizzled k sub-chunk
  const unsigned short* pa0 = Aop + (size_t)srow * DDIM + kcsw;
  const unsigned short* pa1 = pa0 + (size_t)128 * DDIM;
  const unsigned short* pb0 = Bop + (size_t)srow * DDIM + kcsw;
  const unsigned short* pb1 = pb0 + (size_t)128 * DDIM;
  unsigned short* dA = sA + wave * 512;            // + implicit lane*8 shorts
  unsigned short* dB = sB + wave * 512;

  int aoff[8], boff[4];
#pragma unroll
  for (int m = 0; m < 8; ++m)
    aoff[m] = (wr * 128 + m * 16 + lr) * 32 + (lq ^ (lr & 3)) * 8;
#pragma unroll
  for (int n = 0; n < 4; ++n)
    boff[n] = (wc * 64 + n * 16 + lr) * 32 + (lq ^ (lr & 3)) * 8;

  f32x4 acc[8][4];
  f32x4 zero = {0.f, 0.f, 0.f, 0.f};
#pragma unroll
  for (int m = 0; m < 8; ++m)
#pragma unroll
    for (int n = 0; n < 4; ++n) acc[m][n] = zero;

#define SGA(c) { const int sl_ = ((c) & 3) * 8192; \
  gld16(pa0 + (size_t)(c) * 32, dA + sl_); \
  gld16(pa1 + (size_t)(c) * 32, dA + sl_ + 4096); }
#define SGB(c) { const int sl_ = ((c) & 3) * 8192; \
  gld16(pb0 + (size_t)(c) * 32, dB + sl_); \
  gld16(pb1 + (size_t)(c) * 32, dB + sl_ + 4096); }

  // prologue: chunks 0..2 in flight, wait for chunk 0 (oldest 4 ops of 12).
  SGA(0); SGB(0); SGA(1); SGB(1); SGA(2); SGB(2);
  asm volatile("s_waitcnt vmcnt(8)\ns_barrier" ::: "memory");

  for (int j = 0; j < 16; ++j) {
    const int sl = (j & 3) * 8192;
    s16x8 af[8];
#pragma unroll
    for (int m = 0; m < 8; ++m) af[m] = *(const s16x8*)(sA + sl + aoff[m]);
    s16x8 bf0 = *(const s16x8*)(sB + sl + boff[0]);
    s16x8 bf1 = *(const s16x8*)(sB + sl + boff[1]);
    if (j < 13) SGA(j + 3);
    __builtin_amdgcn_s_setprio(1);
#pragma unroll
    for (int m = 0; m < 8; ++m) {
      acc[m][0] = __builtin_amdgcn_mfma_f32_16x16x32_bf16(af[m], bf0, acc[m][0], 0, 0, 0);
      acc[m][1] = __builtin_amdgcn_mfma_f32_16x16x32_bf16(af[m], bf1, acc[m][1], 0, 0, 0);
    }
    __builtin_amdgcn_s_setprio(0);
    asm volatile("s_barrier" ::: "memory");
    s16x8 bf2 = *(const s16x8*)(sB + sl + boff[2]);
    s16x8 bf3 = *(const s16x8*)(sB + sl + boff[3]);
    if (j < 13) SGB(j + 3);
    __builtin_amdgcn_s_setprio(1);
#pragma unroll
    for (int m = 0; m < 8; ++m) {
      acc[m][2] = __builtin_amdgcn_mfma_f32_16x16x32_bf16(af[m], bf2, acc[m][2], 0, 0, 0);
      acc[m][3] = __builtin_amdgcn_mfma_f32_16x16x32_bf16(af[m], bf3, acc[m][3], 0, 0, 0);
    }
    __builtin_amdgcn_s_setprio(0);
    if (j < 13)
      asm volatile("s_waitcnt vmcnt(8)\ns_barrier" ::: "memory");
    else if (j == 13)
      asm volatile("s_waitcnt vmcnt(4)\ns_barrier" ::: "memory");
    else
      asm volatile("s_waitcnt vmcnt(0)\ns_barrier" ::: "memory");
  }
#undef SGA
#undef SGB

  // masks -> LDS after the ring drains (zero vmcnt interference).
  if (tid < 256)
    sMa[tid] = mask_a[b * LSEQ + bi + tid];
  else
    sMb[tid - 256] = mask_b[b * LSEQ + bj + tid - 256];
  __syncthreads();

  const float scale = 0.044194173824159216f;  // 1/sqrt(512)
  unsigned short* Eb = E + (size_t)b * LSEQ * LSEQ + (size_t)bi * LSEQ + bj;
  float rowp[8][4];
  float colp[4] = {0.f, 0.f, 0.f, 0.f};
#pragma unroll
  for (int m = 0; m < 8; ++m) {
#pragma unroll
    for (int rr = 0; rr < 4; ++rr) rowp[m][rr] = 0.f;
#pragma unroll
    for (int n = 0; n < 4; ++n) {
      int jl = wc * 64 + n * 16 + lr;
      int mb_ = sMb[jl];
      s16x4 tq;
#pragma unroll
      for (int rr = 0; rr < 4; ++rr) {
        int il = wr * 128 + m * 16 + lq * 4 + rr;
        float e = (sMa[il] && mb_) ? __expf(acc[m][n][rr] * scale) : 0.f;
        rowp[m][rr] += e;
        colp[n] += e;
        unsigned short eb = f2b(e);
        tq[rr] = (short)eb;
        Eb[(size_t)il * LSEQ + jl] = eb;   // scalar, L2 write-combined
      }
      // write-through to bounce [jl][il^swz]; x=(jl&7)*8 preserves 8-runs
      int il0 = wr * 128 + m * 16 + lq * 4;
      *(s16x4*)(smem + jl * 256 + (il0 ^ ((jl & 7) << 3))) = tq;
    }
  }
#pragma unroll
  for (int m = 0; m < 8; ++m)
#pragma unroll
    for (int rr = 0; rr < 4; ++rr) {
      float v = rowp[m][rr];
      v += __shfl_xor(v, 1);
      v += __shfl_xor(v, 2);
      v += __shfl_xor(v, 4);
      v += __shfl_xor(v, 8);
      if (lr == 0) {
        int il = wr * 128 + m * 16 + lq * 4 + rr;
        atomicAdd(&Zrow[b * LSEQ + bi + il], v);
      }
    }
#pragma unroll
  for (int n = 0; n < 4; ++n) {
    float v = colp[n];
    v += __shfl_xor(v, 16);
    v += __shfl_xor(v, 32);
    if (lq == 0) atomicAdd(&Zcol[b * LSEQ + bj + wc * 64 + n * 16 + lr], v);
  }
  __syncthreads();
  // Et pass: 256 rows x 32 chunks of 16B, coalesced; inverse XOR recovers il.
  unsigned short* EtB = Et + (size_t)b * LSEQ * LSEQ + (size_t)bj * LSEQ + bi;
#pragma unroll
  for (int p = 0; p < 16; ++p) {
    int idx = p * 512 + tid;
    int jlr = idx >> 5, chk = idx & 31;
    s16x8 v = *(const s16x8*)(smem + jlr * 256 + ((chk * 8) ^ ((jlr & 7) << 3)));
    *(s16x8*)(EtB + (size_t)jlr * LSEQ + chk * 8) = v;
  }
}

// out[b,d,i] = (Z[b,i]>0 ? 1/Z[b,i] : 0) * in16[b,i,d], transposed store.
__global__ __launch_bounds__(256) void k_scaleT(const unsigned short* __restrict__ a16,
                                                const unsigned short* __restrict__ b16,
                                                const float* __restrict__ Zrow,
                                                const float* __restrict__ Zcol,
                                                unsigned short* __restrict__ atS,
                                                unsigned short* __restrict__ btS) {
  int zz = blockIdx.z;
  int b = zz & 7, sel = zz >> 3;
  const unsigned short* in = sel ? b16 : a16;
  const float* Z = sel ? Zcol : Zrow;
  unsigned short* out = sel ? btS : atS;
  int i0 = blockIdx.y * 64, d0 = blockIdx.x * 64;
  __shared__ unsigned short lt[64 * 65];
  __shared__ float zinv[64];
  if (threadIdx.x < 64) {
    float z = Z[b * LSEQ + i0 + threadIdx.x];
    zinv[threadIdx.x] = (z > 0.f) ? 1.f / z : 0.f;
  }
  __syncthreads();
  const unsigned short* ib = in + ((size_t)b * LSEQ + i0) * DDIM + d0;
#pragma unroll
  for (int p = 0; p < 16; ++p) {
    int idx = p * 256 + threadIdx.x;
    int dl = idx & 63, il = idx >> 6;
    lt[dl * 65 + il] = f2b(b2f(ib[(size_t)il * DDIM + dl]) * zinv[il]);
  }
  __syncthreads();
  unsigned short* ob = out + ((size_t)b * DDIM + d0) * LSEQ + i0;
#pragma unroll
  for (int p = 0; p < 16; ++p) {
    int idx = p * 256 + threadIdx.x;
    int il = idx & 63, dl = idx >> 6;
    ob[(size_t)dl * LSEQ + il] = lt[dl * 65 + il];
  }
}

// Output GEMMs, 256x256 tile, 8 waves, 8-phase K-chunk ring (T2+T3+T4+T5):
//   mode0: OutA = E  @ btS^T + a16 + Cb
//   mode1: OutB = Et @ atS^T + b16 + Ca
// K-chunk = 32; ring of 4 chunk slots per operand (4x16KB A + 4x16KB B = 128KB).
// Stages lead reads by 3 chunks; counted s_waitcnt vmcnt(8) (never 0 until tail).
// XOR swizzle kc ^= (row&3) on staged source + ds_read deconflicts banks.
// Grid 256 (1 block/CU), 512 threads (2M x 4N waves), 128x64 out per wave.
__global__ __launch_bounds__(512, 2) void k_gemm_outs(
    const unsigned short* __restrict__ E, const unsigned short* __restrict__ Et,
    const unsigned short* __restrict__ btS, const unsigned short* __restrict__ atS,
    const unsigned short* __restrict__ a16, const unsigned short* __restrict__ b16,
    const float* __restrict__ Ca, const float* __restrict__ Cb,
    float* __restrict__ OutA, float* __restrict__ OutB) {
  // XCD swizzle: 32 consecutive work ids per XCD -> 2 full (mode,b) instances/XCD.
  int w = (blockIdx.x & 7) * 32 + (blockIdx.x >> 3);
  int mode = w >> 7;
  int r0 = w & 127;
  int b = r0 >> 4, tile = r0 & 15;
  int bm = (tile >> 1) * 256, bn = (tile & 1) * 256;
  const unsigned short* Aop = (mode ? Et : E) + (size_t)b * LSEQ * LSEQ + (size_t)bm * LSEQ;
  const unsigned short* Bop = (mode ? atS : btS) + (size_t)b * DDIM * LSEQ + (size_t)bn * LSEQ;
  const unsigned short* addin = mode ? b16 : a16;
  const float* Cvec = mode ? Ca : Cb;
  float* Out = mode ? OutB : OutA;

  __shared__ __align__(16) unsigned short sA[4 * 8192], sB[4 * 8192];
  const int tid = threadIdx.x;
  const int wave = tid >> 6, lane = tid & 63;
  const int wr = wave >> 2, wc = wave & 3;
  const int lr = lane & 15, lq = lane >> 4;

  // staging: chunk = [256 rows][32 k] bf16 = 16KB; thread covers 16B at linear
  // LDS offset tid*16 (+8192B for second row-half); source k-chunk XOR-swizzled.
  const int srow = tid >> 2;                       // 0..127
  const int kcsw = ((tid & 3) ^ (srow & 3)) * 8;   // swizzled k sub-chunk
  const unsigned short* pa0 = Aop + (size_t)srow * LSEQ + kcsw;
  const unsigned short* pa1 = pa0 + (size_t)128 * LSEQ;
  const unsigned short* pb0 = Bop + (size_t)srow * LSEQ + kcsw;
  const unsigned short* pb1 = pb0 + (size_t)128 * LSEQ;
  unsigned short* dA = sA + wave * 512;            // + implicit lane*8 shorts
  unsigned short* dB = sB + wave * 512;

  // fragment read offsets (shorts), same XOR swizzle
  int aoff[8], boff[4];
#pragma unroll
  for (int m = 0; m < 8; ++m)
    aoff[m] = (wr * 128 + m * 16 + lr) * 32 + (lq ^ (lr & 3)) * 8;
#pragma unroll
  for (int n = 0; n < 4; ++n)
    boff[n] = (wc * 64 + n * 16 + lr) * 32 + (lq ^ (lr & 3)) * 8;

  f32x4 acc[8][4];
  f32x4 zero = {0.f, 0.f, 0.f, 0.f};
#pragma unroll
  for (int m = 0; m < 8; ++m)
#pragma unroll
    for (int n = 0; n < 4; ++n) acc[m][n] = zero;

#define SGA(c) { const int sl_ = ((c) & 3) * 8192; \
  gld16(pa0 + (size_t)(c) * 32, dA + sl_); \
  gld16(pa1 + (size_t)(c) * 32, dA + sl_ + 4096); }
#define SGB(c) { const int sl_ = ((c) & 3) * 8192; \
  gld16(pb0 + (size_t)(c) * 32, dB + sl_); \
  gld16(pb1 + (size_t)(c) * 32, dB + sl_ + 4096); }

  // prologue: chunks 0..2 in flight, wait for chunk 0 (oldest 4 ops of 12).
  SGA(0); SGB(0); SGA(1); SGB(1); SGA(2); SGB(2);
  asm volatile("s_waitcnt vmcnt(8)\ns_barrier" ::: "memory");

  for (int j = 0; j < 64; ++j) {
    const int sl = (j & 3) * 8192;
    // EVEN phase: af(8) + bf01 reads, stage A(j+3), MFMA n=0,1
    s16x8 af[8];
#pragma unroll
    for (int m = 0; m < 8; ++m) af[m] = *(const s16x8*)(sA + sl + aoff[m]);
    s16x8 bf0 = *(const s16x8*)(sB + sl + boff[0]);
    s16x8 bf1 = *(const s16x8*)(sB + sl + boff[1]);
    if (j < 61) SGA(j + 3);
    __builtin_amdgcn_s_setprio(1);
#pragma unroll
    for (int m = 0; m < 8; ++m) {
      acc[m][0] = __builtin_amdgcn_mfma_f32_16x16x32_bf16(af[m], bf0, acc[m][0], 0, 0, 0);
      acc[m][1] = __builtin_amdgcn_mfma_f32_16x16x32_bf16(af[m], bf1, acc[m][1], 0, 0, 0);
    }
    __builtin_amdgcn_s_setprio(0);
    asm volatile("s_barrier" ::: "memory");
    // ODD phase: bf23 reads, stage B(j+3), MFMA n=2,3, counted wait + barrier
    s16x8 bf2 = *(const s16x8*)(sB + sl + boff[2]);
    s16x8 bf3 = *(const s16x8*)(sB + sl + boff[3]);
    if (j < 61) SGB(j + 3);
    __builtin_amdgcn_s_setprio(1);
#pragma unroll
    for (int m = 0; m < 8; ++m) {
      acc[m][2] = __builtin_amdgcn_mfma_f32_16x16x32_bf16(af[m], bf2, acc[m][2], 0, 0, 0);
      acc[m][3] = __builtin_amdgcn_mfma_f32_16x16x32_bf16(af[m], bf3, acc[m][3], 0, 0, 0);
    }
    __builtin_amdgcn_s_setprio(0);
    if (j < 61)
      asm volatile("s_waitcnt vmcnt(8)\ns_barrier" ::: "memory");
    else if (j == 61)
      asm volatile("s_waitcnt vmcnt(4)\ns_barrier" ::: "memory");
    else
      asm volatile("s_waitcnt vmcnt(0)\ns_barrier" ::: "memory");
  }
#undef SGA
#undef SGB

#pragma unroll
  for (int m = 0; m < 8; ++m)
#pragma unroll
    for (int n = 0; n < 4; ++n)
#pragma unroll
      for (int rr = 0; rr < 4; ++rr) {
        int row = bm + wr * 128 + m * 16 + lq * 4 + rr;
        int col = bn + wc * 64 + n * 16 + lr;
        size_t o = ((size_t)b * LSEQ + row) * DDIM + col;
        Out[o] = acc[m][n][rr] + b2f(addin[o]) + Cvec[b * DDIM + col];
      }
}

extern "C" void kernel_launch(void* const* d_in, const int* in_sizes, int n_in,
                              void* d_out, int out_size, void* d_ws, size_t ws_size,
                              hipStream_t stream) {
  (void)in_sizes; (void)n_in; (void)out_size; (void)ws_size;
  const float* in_a = (const float*)d_in[0];
  const float* in_b = (const float*)d_in[1];
  const int* ma = (const int*)d_in[2];
  const int* mb = (const int*)d_in[3];
  const float* Wa = (const float*)d_in[4];
  const float* ba = (const float*)d_in[5];
  const float* Wb = (const float*)d_in[6];
  const float* bb = (const float*)d_in[7];
  float* out = (float*)d_out;

  char* ws = (char*)d_ws;
  const size_t MB = 1ull << 20;
  unsigned short* a16 = (unsigned short*)(ws + 0 * MB);    // 16MB
  unsigned short* b16 = (unsigned short*)(ws + 16 * MB);   // 16MB
  unsigned short* WaT = (unsigned short*)(ws + 32 * MB);   // 0.5MB
  unsigned short* WbT = (unsigned short*)(ws + 32 * MB + 512 * 1024);
  unsigned short* mapa = (unsigned short*)(ws + 33 * MB);  // 16MB
  unsigned short* mapb = (unsigned short*)(ws + 49 * MB);  // 16MB
  unsigned short* E = (unsigned short*)(ws + 65 * MB);     // 64MB
  unsigned short* atS = (unsigned short*)(ws + 129 * MB);  // 16MB
  unsigned short* btS = (unsigned short*)(ws + 145 * MB);  // 16MB
  float* Zrow = (float*)(ws + 161 * MB);                   // 64KB
  float* Zcol = (float*)(ws + 161 * MB + 65536);           // 64KB
  float* Ca = (float*)(ws + 161 * MB + 2 * 65536);         // 16KB
  float* Cb = (float*)(ws + 161 * MB + 2 * 65536 + 16384); // 16KB
  unsigned short* Et = (unsigned short*)(ws + 164 * MB);   // 64MB

  // Zrow + Zcol + Ca + Cb are contiguous: one memset covers all (160KB).
  hipMemsetAsync(Zrow, 0, 2 * 65536 + 2 * 16384, stream);
  k_prep<<<dim3(64, 8, 2), 256, 0, stream>>>(in_a, in_b, ma, mb, a16, b16, Ca, Cb);
  k_transposeW<<<2048, 256, 0, stream>>>(Wa, Wb, WaT, WbT);
  k_gemm_bias<<<256, 512, 0, stream>>>(a16, b16, WaT, WbT, ba, bb, mapa, mapb);
  k_scores<<<512, 512, 0, stream>>>(mapa, mapb, ma, mb, E, Et, Zrow, Zcol);
  k_scaleT<<<dim3(8, 32, 16), 256, 0, stream>>>(a16, b16, Zrow, Zcol, atS, btS);
  k_gemm_outs<<<256, 512, 0, stream>>>(E, Et, btS, atS, a16, b16, Ca, Cb,
                                       out, out + (size_t)BATCH * LSEQ * DDIM);
}